// Round 11
// baseline (353.520 us; speedup 1.0000x reference)
//
#include <hip/hip_runtime.h>

#define N_TOTAL 409600

typedef short short8 __attribute__((ext_vector_type(8)));
typedef float floatx4 __attribute__((ext_vector_type(4)));

__device__ __forceinline__ unsigned short f2bf_rne(float f) {
    unsigned u = __float_as_uint(f);
    u += 0x7fffu + ((u >> 16) & 1u);
    return (unsigned short)(u >> 16);
}

// One wave = 4 tiles of 16 consecutive voxels (tiles never cross a w-row:
// all R are multiples of 16). A: fp32 global -> reg -> cvt_pk bf16.
// B: bf16 fragments preloaded from LDS (staged once per block).
template <int R>
__device__ __forceinline__ void conv_dev(const float* __restrict__ in_lvl,
                                         const unsigned short* __restrict__ wlds,
                                         const float* __restrict__ bias,
                                         float* __restrict__ out_lvl,
                                         int lv0) {
    const int lane   = threadIdx.x & 63;
    const int q      = lane >> 4;
    const int r      = lane & 15;          // A-row: voxel; C/D col: cout
    const int tapSel = q >> 1;
    const int ciHalf = (q & 1) * 8;

    // B fragments once per wave: lane-contiguous 16B ds_reads, conflict-free
    short8 bf[14];
#pragma unroll
    for (int p = 0; p < 14; ++p)
        bf[p] = *(const short8*)(wlds + (p * 64 + lane) * 8);

    const float bv = bias[r];

#pragma unroll 1            // keep code size down; ILP lives inside one tile
    for (int t = 0; t < 4; ++t) {
        const int lv = lv0 + t * 16;
        const int d  = lv / (R * R);
        const int h  = (lv / R) % R;
        const int w0 = lv % R;             // multiple of 16
        const int zw = w0 + r;             // this lane's voxel w

        const bool wvm = (zw >= 1);        // kw=0 (w-1) valid
        const bool wvp = (zw + 1 < R);     // kw=2 (w+1) valid

        const float* base = in_lvl + (size_t)(lv + r) * 16 + ciHalf;

        short8 abf[14];

        // two sub-batches: 7 taps loaded (14 float4 in flight), then converted
#pragma unroll
        for (int half = 0; half < 2; ++half) {
            float4 rlo[7], rhi[7];
            unsigned msk[7];
#pragma unroll
            for (int pp = 0; pp < 7; ++pp) {
                const int p  = half * 7 + pp;
                const int t0 = 2 * p;
                const int t1 = (2 * p + 1 < 27) ? 2 * p + 1 : 26;  // pair-13 hi: B=0
                const int kd0 = t0 / 9, kh0 = (t0 / 3) % 3, kw0 = t0 % 3;
                const int kd1 = t1 / 9, kh1 = (t1 / 3) % 3, kw1 = t1 % 3;
                const bool v0 = ((unsigned)(d + kd0 - 1) < (unsigned)R) &&
                                ((unsigned)(h + kh0 - 1) < (unsigned)R) &&
                                (kw0 == 0 ? wvm : (kw0 == 2 ? wvp : true));
                const bool v1 = ((unsigned)(d + kd1 - 1) < (unsigned)R) &&
                                ((unsigned)(h + kh1 - 1) < (unsigned)R) &&
                                (kw1 == 0 ? wvm : (kw1 == 2 ? wvp : true));
                const bool v  = tapSel ? v1 : v0;
                const int off0 = (((kd0 - 1) * R + (kh0 - 1)) * R + (kw0 - 1)) * 16;
                const int off1 = (((kd1 - 1) * R + (kh1 - 1)) * R + (kw1 - 1)) * 16;
                const int off  = tapSel ? off1 : off0;
                const float* ap = v ? (base + off) : base;   // safe dummy addr
                rlo[pp] = ((const float4*)ap)[0];
                rhi[pp] = ((const float4*)ap)[1];
                msk[pp] = v ? 0xffffffffu : 0u;
            }
#pragma unroll
            for (int pp = 0; pp < 7; ++pp) {
                const int p = half * 7 + pp;
                unsigned u0, u1, u2, u3;
                asm("v_cvt_pk_bf16_f32 %0, %1, %2" : "=v"(u0) : "v"(rlo[pp].x), "v"(rlo[pp].y));
                asm("v_cvt_pk_bf16_f32 %0, %1, %2" : "=v"(u1) : "v"(rlo[pp].z), "v"(rlo[pp].w));
                asm("v_cvt_pk_bf16_f32 %0, %1, %2" : "=v"(u2) : "v"(rhi[pp].x), "v"(rhi[pp].y));
                asm("v_cvt_pk_bf16_f32 %0, %1, %2" : "=v"(u3) : "v"(rhi[pp].z), "v"(rhi[pp].w));
                union { short8 s; unsigned u[4]; } pk;
                pk.u[0] = u0 & msk[pp];
                pk.u[1] = u1 & msk[pp];
                pk.u[2] = u2 & msk[pp];
                pk.u[3] = u3 & msk[pp];
                abf[p] = pk.s;
            }
        }

        floatx4 acc = {bv, bv, bv, bv};
#pragma unroll
        for (int p = 0; p < 14; ++p)
            acc = __builtin_amdgcn_mfma_f32_16x16x32_bf16(abf[p], bf[p], acc, 0, 0, 0);

        float* dst = out_lvl + (size_t)lv * 16;
#pragma unroll
        for (int j = 0; j < 4; ++j)
            dst[(size_t)(q * 4 + j) * 16 + r] = acc[j];
    }
}

__global__ __launch_bounds__(256) __attribute__((amdgpu_waves_per_eu(2, 3)))
void conv_fused(const float* __restrict__ in, const float* __restrict__ w,
                const float* __restrict__ bias, float* __restrict__ out) {
    // stage B fragments into LDS: pair p, lane l, j: k = tapSel*16+ci layout
    __shared__ unsigned short wlds[7168];   // 14 KiB
#pragma unroll
    for (int k = threadIdx.x; k < 7168; k += 256) {
        const int j    = k & 7;
        const int lane = (k >> 3) & 63;
        const int p    = k >> 9;
        const int qq   = lane >> 4;
        const int tap  = 2 * p + (qq >> 1);
        const int ci   = (qq & 1) * 8 + j;
        const int co   = lane & 15;
        const float v  = (tap < 27) ? w[(co * 16 + ci) * 27 + tap] : 0.0f;
        wlds[k] = f2bf_rne(v);
    }
    __syncthreads();

    const int b  = blockIdx.y;
    const int v0 = blockIdx.x * 256 + (int)(threadIdx.x >> 6) * 64;
    const size_t bb = (size_t)b * N_TOTAL * 16;

    // level boundaries (4096 / 36864 / 147456) are multiples of 256
    if (v0 < 4096) {
        conv_dev<16>(in + bb, wlds, bias, out + bb, v0);
    } else if (v0 < 36864) {
        conv_dev<32>(in + bb + (size_t)4096 * 16, wlds, bias,
                     out + bb + (size_t)4096 * 16, v0 - 4096);
    } else if (v0 < 147456) {
        conv_dev<48>(in + bb + (size_t)36864 * 16, wlds, bias,
                     out + bb + (size_t)36864 * 16, v0 - 36864);
    } else {
        conv_dev<64>(in + bb + (size_t)147456 * 16, wlds, bias,
                     out + bb + (size_t)147456 * 16, v0 - 147456);
    }
}

extern "C" void kernel_launch(void* const* d_in, const int* in_sizes, int n_in,
                              void* d_out, int out_size, void* d_ws, size_t ws_size,
                              hipStream_t stream) {
    const float* in   = (const float*)d_in[0];
    const float* wgt  = (const float*)d_in[1];
    const float* bias = (const float*)d_in[2];
    float* out = (float*)d_out;
    (void)d_ws; (void)ws_size; (void)in_sizes; (void)n_in; (void)out_size;

    // 409600 voxels / 256 per block = 1600 blocks; y = batch
    conv_fused<<<dim3(1600, 4), 256, 0, stream>>>(in, wgt, bias, out);
}